// Round 6
// baseline (799.551 us; speedup 1.0000x reference)
//
#include <hip/hip_runtime.h>
#include <cmath>

// node_learning: out = tanh((adj @ X) @ Wn^T + X @ Ws^T)
// Fold: (adj@X)@Wn^T == adj@(X@Wn^T).  Big GEMM in bf16 hi/lo split
// (3 MFMA passes: hh + hl + lh, rel err ~2^-17) -> memory-bound,
// adj-read floor ~63us HBM (L3 absorbs part; FETCH shows ~220-260MB).
// History: R4 m97 K-loop w/ global_load_lds = 190us. R5 fused-epi
// fence thrash (REVERTED). R6 depth-2 dbuf: NEUTRAL (drain just moved).
// R7 direct-B + gload_lds: FIFO vmcnt serialization, 312 (REVERTED).
// R8 M=128@(256,4): VGPR spill, 433 (REVERTED). R9 M=64 6blk/CU: 206 --
// occupancy refuted; B-staging doubled; LDS pipe + vmcnt(0) drain is the
// structural tax of ALL staged variants (best R2=161us, ~2.4x floor).
// R10 (this): NO LDS AT ALL. A streamed once straight to registers
// (wave-instr touches 16 full 128B lines -> coalesced); B register-direct
// from L2-hot xnt (5.2MB panel reread 79x; 4x/block = 1.7GB L2 ~49us
// aggregate, overlapped). No barriers, no vmcnt(0) drains; compiler
// pipelines register loads with counted waits (R3's failure was the
// gload_lds FIFO mix, which no longer exists). Per wave: 32 A-rows x all
// 128 cols, acc[2][8], B in two 4-col half-batches to cap live VGPRs.
// Grid 79x8=632 blocks -> single dispatch round. Same k/mfma order as R9
// -> bit-identical output (absmax 0.00390625).

#define N_NODES 10000
#define EMB 128
#define XNT_STRIDE 10240   // padded row length (elems) of transposed Xn
#define KC 1280            // K-chunk per block (mult of 32: interior chunks
                           // must not overreach; only last chunk hits pad)
#define NKCH 8             // ceil(10000/1280)

typedef __bf16 bf16x8 __attribute__((ext_vector_type(8)));
typedef float  f32x4  __attribute__((ext_vector_type(4)));

// split 8 fp32 into bf16 hi + bf16 lo(residual)
__device__ __forceinline__ void split8(const float4& x0, const float4& x1,
                                       bf16x8& h, bf16x8& l) {
    float f[8] = {x0.x, x0.y, x0.z, x0.w, x1.x, x1.y, x1.z, x1.w};
#pragma unroll
    for (int i = 0; i < 8; ++i) {
        __bf16 hh = (__bf16)f[i];
        h[i] = hh;
        l[i] = (__bf16)(f[i] - (float)hh);
    }
}

// ---------------------------------------------------------------------------
// prep: Xn = X @ Wn^T  (fp32), split to bf16 hi/lo, store transposed
// xnt[c][n], row stride XNT_STRIDE.  Block 0 also zeroes the k-pad region
// [10000, 10240) of every column (read by gemm's last K-chunk overreach).
// ---------------------------------------------------------------------------
__global__ __launch_bounds__(256) void prep_kernel(
    const float* __restrict__ X, const float* __restrict__ Wn,
    __bf16* __restrict__ xnt_hi, __bf16* __restrict__ xnt_lo)
{
    __shared__ float Xl[32 * EMB];
    const int tid = threadIdx.x;
    const int n0 = blockIdx.x * 32;

    if (blockIdx.x == 0) {
        // zero pad region: 128 cols x 240 elems = 3840 groups of 8
        bf16x8 z;
#pragma unroll
        for (int i = 0; i < 8; ++i) z[i] = (__bf16)0.0f;
        for (int g = tid; g < 128 * 30; g += 256) {
            int col = g / 30, j = g % 30;
            size_t off = (size_t)col * XNT_STRIDE + N_NODES + j * 8;
            *(bf16x8*)(xnt_hi + off) = z;
            *(bf16x8*)(xnt_lo + off) = z;
        }
    }

#pragma unroll
    for (int i = 0; i < 4; ++i) {
        int idx = tid + i * 256;            // float4 index 0..1023
        int r = idx >> 5;
        int c4 = (idx & 31) << 2;
        int row = n0 + r;
        float4 v = make_float4(0.f, 0.f, 0.f, 0.f);
        if (row < N_NODES) v = *(const float4*)(X + (size_t)row * EMB + c4);
        *(float4*)(Xl + r * EMB + c4) = v;
    }
    __syncthreads();

    const int c = tid & 127;
    const int half = tid >> 7;
    const float* wrow = Wn + c * EMB;

    float acc[16];
#pragma unroll
    for (int r = 0; r < 16; ++r) acc[r] = 0.f;

    for (int k4 = 0; k4 < 32; ++k4) {
        float4 w = *(const float4*)(wrow + k4 * 4);
#pragma unroll
        for (int r = 0; r < 16; ++r) {
            float4 x = *(const float4*)(Xl + (half * 16 + r) * EMB + k4 * 4);
            acc[r] += x.x * w.x + x.y * w.y + x.z * w.z + x.w * w.w;
        }
    }

    // rows n0+half*16 .. +15 all valid or all invalid (10000 % 16 == 0)
    if (n0 + half * 16 < N_NODES) {
        bf16x8 h0, h1, l0, l1;
#pragma unroll
        for (int r = 0; r < 16; ++r) {
            float f = acc[r];
            __bf16 h = (__bf16)f;
            __bf16 l = (__bf16)(f - (float)h);
            if (r < 8) { h0[r] = h; l0[r] = l; }
            else       { h1[r - 8] = h; l1[r - 8] = l; }
        }
        size_t base = (size_t)c * XNT_STRIDE + n0 + half * 16;
        *(bf16x8*)(xnt_hi + base)     = h0;
        *(bf16x8*)(xnt_hi + base + 8) = h1;
        *(bf16x8*)(xnt_lo + base)     = l0;
        *(bf16x8*)(xnt_lo + base + 8) = l1;
    }
}

// ---------------------------------------------------------------------------
// gemm: P[kc] = adj[m0:m0+128, kc range] @ Xn[kc range, :]
// Register-direct, zero LDS, zero barriers.  4 waves, wave owns rows
// wm = wave*32 (A read once per block) x all 128 output cols.
// Per K-step(32): A = adj[row][k0+q*8 ..+7] (two float4), split to hi/lo;
// B = xnt[col][same k] (bf16x8, contiguous: xnt k-major).  B pad
// [10000,10240) is zero, so last-chunk overreach contributes 0 (A address
// clamped into valid range; value irrelevant).
// ---------------------------------------------------------------------------
__global__ __launch_bounds__(256) void gemm_kernel(
    const float* __restrict__ adj, const __bf16* __restrict__ xnt_hi,
    const __bf16* __restrict__ xnt_lo, float* __restrict__ Ppart)
{
    const int tid = threadIdx.x;
    const int m0 = blockIdx.x * 128;
    const int kc0 = blockIdx.y * KC;
    const int kc_end = min(kc0 + KC, N_NODES);
    const int nsub = (kc_end - kc0 + 31) >> 5;

    const int lane = tid & 63;
    const int wave = tid >> 6;
    const int wm = wave * 32;          // wave's 32 rows
    const int fr = lane & 15;          // row (A) / col (B) within 16-tile
    const int q  = lane >> 4;          // k-quad (8 elems)

    // A row base pointers (rows read exactly once per block)
    const float* arow[2];
#pragma unroll
    for (int mt = 0; mt < 2; ++mt) {
        int r = m0 + wm + mt * 16 + fr;
        if (r >= N_NODES) r = 0;       // dupes ok; stores are guarded
        arow[mt] = adj + (size_t)r * N_NODES;
    }

    // B per-lane column base offsets (elements); col = nt*16 + fr
    size_t bcol[8];
#pragma unroll
    for (int nt = 0; nt < 8; ++nt)
        bcol[nt] = (size_t)(nt * 16 + fr) * XNT_STRIDE;

    f32x4 acc[2][8];
#pragma unroll
    for (int mt = 0; mt < 2; ++mt)
#pragma unroll
        for (int nt = 0; nt < 8; ++nt)
#pragma unroll
            for (int e = 0; e < 4; ++e) acc[mt][nt][e] = 0.f;

    for (int ks = 0; ks < nsub; ++ks) {
        const int k0 = kc0 + ks * 32;
        const int ka = k0 + q * 8;               // lane's 8-elem k offset
        // A clamp: kc_end % 8 == 0, so a fragment is either fully valid or
        // fully in the pad zone; pad-zone A pairs with zero B -> clamp addr.
        const int kaA = (ka >= kc_end) ? kc0 : ka;

        // ---- A fragments straight from global (16 full lines / instr) ----
        bf16x8 ah[2], al[2];
#pragma unroll
        for (int mt = 0; mt < 2; ++mt) {
            float4 fa = *(const float4*)(arow[mt] + kaA);
            float4 fb = *(const float4*)(arow[mt] + kaA + 4);
            split8(fa, fb, ah[mt], al[mt]);
        }

        // ---- B in two 4-col half-batches (caps live VGPRs) ----
#pragma unroll
        for (int h = 0; h < 2; ++h) {
            bf16x8 bh[4], bl[4];
#pragma unroll
            for (int j = 0; j < 4; ++j) {
                size_t boff = bcol[h * 4 + j] + ka;
                bh[j] = *(const bf16x8*)(xnt_hi + boff);
                bl[j] = *(const bf16x8*)(xnt_lo + boff);
            }
#pragma unroll
            for (int mt = 0; mt < 2; ++mt)
#pragma unroll
                for (int j = 0; j < 4; ++j) {
                    const int nt = h * 4 + j;
                    acc[mt][nt] = __builtin_amdgcn_mfma_f32_16x16x32_bf16(ah[mt], bh[j], acc[mt][nt], 0, 0, 0);
                    acc[mt][nt] = __builtin_amdgcn_mfma_f32_16x16x32_bf16(ah[mt], bl[j], acc[mt][nt], 0, 0, 0);
                    acc[mt][nt] = __builtin_amdgcn_mfma_f32_16x16x32_bf16(al[mt], bh[j], acc[mt][nt], 0, 0, 0);
                }
        }
    }

    // C/D layout (verified m89): col = lane&15, row = (lane>>4)*4 + reg
    float* P = Ppart + (size_t)blockIdx.y * ((size_t)N_NODES * EMB);
#pragma unroll
    for (int mt = 0; mt < 2; ++mt) {
        int rbase = m0 + wm + mt * 16 + q * 4;
#pragma unroll
        for (int nt = 0; nt < 8; ++nt) {
            int col = nt * 16 + fr;
#pragma unroll
            for (int r = 0; r < 4; ++r) {
                int row = rbase + r;
                if (row < N_NODES)
                    P[(size_t)row * EMB + col] = acc[mt][nt][r];
            }
        }
    }
}

// ---------------------------------------------------------------------------
// epi (fast path): out = tanh(sum_p P[p] + X @ Ws^T)
// ---------------------------------------------------------------------------
__global__ __launch_bounds__(256) void epi_kernel(
    const float* __restrict__ X, const float* __restrict__ Wself,
    const float* __restrict__ Ppart, float* __restrict__ out)
{
    __shared__ float Xl[32 * EMB];
    const int tid = threadIdx.x;
    const int n0 = blockIdx.x * 32;

#pragma unroll
    for (int i = 0; i < 4; ++i) {
        int idx = tid + i * 256;
        int r = idx >> 5;
        int c4 = (idx & 31) << 2;
        int row = n0 + r;
        float4 v = make_float4(0.f, 0.f, 0.f, 0.f);
        if (row < N_NODES) v = *(const float4*)(X + (size_t)row * EMB + c4);
        *(float4*)(Xl + r * EMB + c4) = v;
    }
    __syncthreads();

    const int c = tid & 127;
    const int half = tid >> 7;
    const float* wrow = Wself + c * EMB;

    float acc[16];
#pragma unroll
    for (int r = 0; r < 16; ++r) acc[r] = 0.f;

    for (int k4 = 0; k4 < 32; ++k4) {
        float4 w = *(const float4*)(wrow + k4 * 4);
#pragma unroll
        for (int r = 0; r < 16; ++r) {
            float4 x = *(const float4*)(Xl + (half * 16 + r) * EMB + k4 * 4);
            acc[r] += x.x * w.x + x.y * w.y + x.z * w.z + x.w * w.w;
        }
    }

    if (n0 + half * 16 < N_NODES) {   // whole 16-row group valid (10000%16==0)
        const size_t rb = (size_t)(n0 + half * 16) * EMB + c;
        // reduce the K-chunk partials (coalesced: lanes span c)
#pragma unroll
        for (int p = 0; p < NKCH; ++p) {
            const float* Pp = Ppart + (size_t)p * ((size_t)N_NODES * EMB) + rb;
#pragma unroll
            for (int r = 0; r < 16; ++r)
                acc[r] += Pp[(size_t)r * EMB];
        }
#pragma unroll
        for (int r = 0; r < 16; ++r)
            out[rb + (size_t)r * EMB] = tanhf(acc[r]);
    }
}

// ---------------------------------------------------------------------------
// Fallback path (ws too small): fp32 VALU GEMM Y = adj@X atomically into out,
// then epi0 applies both weight matrices + tanh.
// ---------------------------------------------------------------------------
__global__ __launch_bounds__(256) void gemm0_kernel(
    const float* __restrict__ adj, const float* __restrict__ X,
    float* __restrict__ Y)
{
    __shared__ float As[128 * 33];
    __shared__ float Xs[32 * 132];
    const int tid = threadIdx.x;
    const int m0 = blockIdx.x * 128;
    const int kc0 = blockIdx.y * KC;
    const int kc_end = min(kc0 + KC, N_NODES);
    const int nsub = (kc_end - kc0 + 31) >> 5;

    const int am = tid >> 1, akq = tid & 1;
    const bool arv = (m0 + am) < N_NODES;
    const float* arow_p = adj + (size_t)(m0 + am) * N_NODES;
    const int xr = tid >> 3, xq = tid & 7;
    const int mq = tid >> 4, nq = tid & 15;

    float acc[8][8];
#pragma unroll
    for (int i = 0; i < 8; ++i)
#pragma unroll
        for (int j = 0; j < 8; ++j) acc[i][j] = 0.f;

    for (int ks = 0; ks < nsub; ++ks) {
        int k0 = kc0 + ks * 32;
#pragma unroll
        for (int i = 0; i < 4; ++i) {
            int k = k0 + akq * 16 + i * 4;
            float4 v = make_float4(0.f, 0.f, 0.f, 0.f);
            if (arv && k < kc_end) v = *(const float4*)(arow_p + k);
            float* d = As + am * 33 + akq * 16 + i * 4;
            d[0] = v.x; d[1] = v.y; d[2] = v.z; d[3] = v.w;
        }
#pragma unroll
        for (int i = 0; i < 4; ++i) {
            int c0 = xq * 16 + i * 4;
            int krow = k0 + xr;
            float4 v = make_float4(0.f, 0.f, 0.f, 0.f);
            if (krow < kc_end) v = *(const float4*)(X + (size_t)krow * EMB + c0);
            *(float4*)(Xs + xr * 132 + c0) = v;
        }
        __syncthreads();
        for (int k = 0; k < 32; ++k) {
            float a8[8];
#pragma unroll
            for (int i = 0; i < 8; ++i) a8[i] = As[(mq * 8 + i) * 33 + k];
            float4 x0 = *(const float4*)(Xs + k * 132 + nq * 8);
            float4 x1 = *(const float4*)(Xs + k * 132 + nq * 8 + 4);
            float x8[8] = { x0.x, x0.y, x0.z, x0.w, x1.x, x1.y, x1.z, x1.w };
#pragma unroll
            for (int i = 0; i < 8; ++i)
#pragma unroll
                for (int j = 0; j < 8; ++j) acc[i][j] += a8[i] * x8[j];
        }
        __syncthreads();
    }
#pragma unroll
    for (int i = 0; i < 8; ++i) {
        int row = m0 + mq * 8 + i;
        if (row < N_NODES) {
#pragma unroll
            for (int j = 0; j < 8; ++j)
                atomicAdd(Y + (size_t)row * EMB + nq * 8 + j, acc[i][j]);
        }
    }
}

__global__ __launch_bounds__(256) void epi0_kernel(
    const float* __restrict__ X, const float* __restrict__ Wn,
    const float* __restrict__ Ws, float* __restrict__ out)
{
    __shared__ float Xl[32 * EMB];
    __shared__ float Yl[32 * EMB];
    const int tid = threadIdx.x;
    const int n0 = blockIdx.x * 32;

#pragma unroll
    for (int i = 0; i < 4; ++i) {
        int idx = tid + i * 256;
        int r = idx >> 5;
        int c4 = (idx & 31) << 2;
        int row = n0 + r;
        float4 vx = make_float4(0.f, 0.f, 0.f, 0.f);
        float4 vy = vx;
        if (row < N_NODES) {
            vx = *(const float4*)(X + (size_t)row * EMB + c4);
            vy = *(const float4*)(out + (size_t)row * EMB + c4);
        }
        *(float4*)(Xl + r * EMB + c4) = vx;
        *(float4*)(Yl + r * EMB + c4) = vy;
    }
    __syncthreads();

    const int c = tid & 127;
    const int half = tid >> 7;
    const float* wn = Wn + c * EMB;
    const float* ws = Ws + c * EMB;

    float accn[16], accs[16];
#pragma unroll
    for (int r = 0; r < 16; ++r) { accn[r] = 0.f; accs[r] = 0.f; }

    for (int k4 = 0; k4 < 32; ++k4) {
        float4 a = *(const float4*)(wn + k4 * 4);
        float4 b = *(const float4*)(ws + k4 * 4);
#pragma unroll
        for (int r = 0; r < 16; ++r) {
            float4 y = *(const float4*)(Yl + (half * 16 + r) * EMB + k4 * 4);
            float4 x = *(const float4*)(Xl + (half * 16 + r) * EMB + k4 * 4);
            accn[r] += y.x * a.x + y.y * a.y + y.z * a.z + y.w * a.w;
            accs[r] += x.x * b.x + x.y * b.y + x.z * b.z + x.w * b.w;
        }
    }
#pragma unroll
    for (int r = 0; r < 16; ++r) {
        int row = n0 + half * 16 + r;
        if (row < N_NODES)
            out[(size_t)row * EMB + c] = tanhf(accn[r] + accs[r]);
    }
}

// ---------------------------------------------------------------------------
extern "C" void kernel_launch(void* const* d_in, const int* in_sizes, int n_in,
                              void* d_out, int out_size, void* d_ws, size_t ws_size,
                              hipStream_t stream) {
    const float* adj = (const float*)d_in[0];
    const float* X   = (const float*)d_in[1];
    const float* Wn  = (const float*)d_in[2];
    const float* Ws  = (const float*)d_in[3];
    float* out = (float*)d_out;

    const size_t xnt_elems = (size_t)EMB * XNT_STRIDE;
    const size_t xnt_bytes = xnt_elems * 2 * sizeof(unsigned short);   // hi+lo
    const size_t part_bytes = (size_t)NKCH * N_NODES * EMB * sizeof(float);

    if (ws_size >= xnt_bytes + part_bytes) {
        // fast path: partials in ws, no atomics, no d_out memset
        __bf16* xh = (__bf16*)d_ws;
        __bf16* xl = xh + xnt_elems;
        float* Ppart = (float*)((char*)d_ws + xnt_bytes);
        prep_kernel<<<(N_NODES + 31) / 32, 256, 0, stream>>>(X, Wn, xh, xl);
        gemm_kernel<<<dim3((N_NODES + 127) / 128, NKCH), 256, 0, stream>>>(adj, xh, xl, Ppart);
        epi_kernel<<<(N_NODES + 31) / 32, 256, 0, stream>>>(X, Ws, Ppart, out);
    } else {
        // fallback: fp32 VALU GEMM with atomics into pre-zeroed out
        hipMemsetAsync(d_out, 0, (size_t)N_NODES * EMB * sizeof(float), stream);
        gemm0_kernel<<<dim3((N_NODES + 127) / 128, NKCH), 256, 0, stream>>>(adj, X, out);
        epi0_kernel<<<(N_NODES + 31) / 32, 256, 0, stream>>>(X, Wn, Ws, out);
    }
}